// Round 3
// baseline (973.776 us; speedup 1.0000x reference)
//
#include <hip/hip_runtime.h>
#include <hip/hip_bf16.h>

// ---------------------------------------------------------------------------
// GCN forward, restructured:  per layer  h' = ReLU( (Â h) @ W + b )
// Aggregation is channel-chunked: each grid.y slice gathers a 16-channel
// (64-byte = one cache line) slice of X, so the per-pass gather working set
// (3.2 MB) is L2-resident per XCD (4 MiB). Epilogue emits bf16 hi/lo split;
// GEMM runs 3-pass bf16 MFMA (hi*hi + hi*lo + lo*hi) ~= fp32 accuracy.
// CSR built on-device each launch; no atomics in per-channel hot paths.
// ---------------------------------------------------------------------------

#define THREADS 256

typedef short bf16x8 __attribute__((ext_vector_type(8)));
typedef float f32x4  __attribute__((ext_vector_type(4)));

__device__ __forceinline__ unsigned bf16_rne_bits(float f) {
    unsigned x = __float_as_uint(f);
    return (x + 0x7fffu + ((x >> 16) & 1u)) >> 16;
}

// ---------------- small setup kernels ----------------

__global__ void degree_kernel(const int* __restrict__ col, int* __restrict__ deg, int E) {
    int e = blockIdx.x * THREADS + threadIdx.x;
    if (e < E) atomicAdd(&deg[col[e]], 1);
}

__global__ void dis_kernel(const int* __restrict__ deg, float* __restrict__ dis, int N) {
    int i = blockIdx.x * THREADS + threadIdx.x;
    if (i < N) dis[i] = rsqrtf((float)(deg[i] + 1));   // +1 self-loop
}

// single-block exclusive scan, 4 elements/thread/iter. out has n+1 slots.
__global__ void exscan_kernel(const int* __restrict__ in, int* __restrict__ out, int n) {
    __shared__ int wsum[4];
    __shared__ int carry_s;
    if (threadIdx.x == 0) carry_s = 0;
    __syncthreads();
    int lane = threadIdx.x & 63, wid = threadIdx.x >> 6;
    for (int base = 0; base < n; base += THREADS * 4) {
        int i0 = base + threadIdx.x * 4;
        int v0 = 0, v1 = 0, v2 = 0, v3 = 0;
        if (i0 + 3 < n) {
            int4 v = *(const int4*)&in[i0];
            v0 = v.x; v1 = v.y; v2 = v.z; v3 = v.w;
        } else {
            if (i0 + 0 < n) v0 = in[i0 + 0];
            if (i0 + 1 < n) v1 = in[i0 + 1];
            if (i0 + 2 < n) v2 = in[i0 + 2];
            if (i0 + 3 < n) v3 = in[i0 + 3];
        }
        int s = v0 + v1 + v2 + v3;
        int inc = s;
        #pragma unroll
        for (int d = 1; d < 64; d <<= 1) {
            int t = __shfl_up(inc, d);
            if (lane >= d) inc += t;
        }
        if (lane == 63) wsum[wid] = inc;
        __syncthreads();
        int add = carry_s;
        for (int w = 0; w < wid; ++w) add += wsum[w];
        int ex = add + inc - s;
        if (i0 + 0 < n) out[i0 + 0] = ex;
        if (i0 + 1 < n) out[i0 + 1] = ex + v0;
        if (i0 + 2 < n) out[i0 + 2] = ex + v0 + v1;
        if (i0 + 3 < n) out[i0 + 3] = ex + v0 + v1 + v2;
        __syncthreads();
        if (threadIdx.x == 0) carry_s += wsum[0] + wsum[1] + wsum[2] + wsum[3];
        __syncthreads();
    }
    if (threadIdx.x == 0) out[n] = carry_s;
}

// uses deg as the countdown (deg no longer needed after dis_kernel)
__global__ void csr_fill_kernel(const int* __restrict__ row, const int* __restrict__ col,
                                const int* __restrict__ offs, int* __restrict__ deg,
                                int* __restrict__ srcs, int E) {
    int e = blockIdx.x * THREADS + threadIdx.x;
    if (e < E) {
        int c = col[e];
        int old = atomicSub(&deg[c], 1);
        srcs[offs[c] + old - 1] = row[e];
    }
}

__global__ void gcount_kernel(const int* __restrict__ batch, int* __restrict__ gcnt, int N) {
    int i = blockIdx.x * THREADS + threadIdx.x;
    if (i < N) atomicAdd(&gcnt[batch[i]], 1);
}

// W[K,N] fp32 -> transposed bf16 hi/lo  Thi/Tlo[N][K]
__global__ void wsplit_kernel(const float* __restrict__ W, unsigned short* __restrict__ Thi,
                              unsigned short* __restrict__ Tlo, int K, int Nc) {
    int i = blockIdx.x * THREADS + threadIdx.x;
    if (i >= K * Nc) return;
    int k = i / Nc, n = i % Nc;
    float w = W[i];
    unsigned hb = bf16_rne_bits(w);
    float hf = __uint_as_float(hb << 16);
    unsigned lb = bf16_rne_bits(w - hf);
    Thi[n * K + k] = (unsigned short)hb;
    Tlo[n * K + k] = (unsigned short)lb;
}

// ---- aggregation: a[i] = dis[i]*(dis[i]*x[i] + sum dis[s]*x[s]) -------------
// channel-chunked: blockIdx.y selects a 16-channel slice; 4 lanes/node gather
// one 64-B line per edge. Per-pass gather set = N*64B = 3.2 MB -> L2-resident.
// Emits bf16 hi/lo split of the result (A operand of the following GEMM).

template<int CH4>   // CH4 = channels/4 (row length in float4s)
__global__ __launch_bounds__(256) void aggregate_chunk_kernel(
    const float* __restrict__ X, const int* __restrict__ offs,
    const int* __restrict__ srcs, const float* __restrict__ dis,
    unsigned short* __restrict__ Ahi, unsigned short* __restrict__ Alo, int N) {
    int group = threadIdx.x >> 2;        // 64 node-groups per block
    int lane  = threadIdx.x & 3;         // 4 lanes -> 4 float4 = 16 channels
    int node  = blockIdx.x * 64 + group;
    if (node >= N) return;
    int c4 = blockIdx.y * 4 + lane;
    const float4* Xv = (const float4*)X;
    float dn = dis[node];
    float4 self = Xv[(size_t)node * CH4 + c4];
    float4 acc, acc2;
    acc.x = dn * self.x; acc.y = dn * self.y;
    acc.z = dn * self.z; acc.w = dn * self.w;
    acc2.x = acc2.y = acc2.z = acc2.w = 0.f;
    int s = offs[node], e = offs[node + 1];
    int i = s;
    for (; i + 2 <= e; i += 2) {
        int s0 = srcs[i], s1 = srcs[i + 1];
        float d0 = dis[s0], d1 = dis[s1];
        float4 v0 = Xv[(size_t)s0 * CH4 + c4];
        float4 v1 = Xv[(size_t)s1 * CH4 + c4];
        acc.x = fmaf(d0, v0.x, acc.x);   acc.y = fmaf(d0, v0.y, acc.y);
        acc.z = fmaf(d0, v0.z, acc.z);   acc.w = fmaf(d0, v0.w, acc.w);
        acc2.x = fmaf(d1, v1.x, acc2.x); acc2.y = fmaf(d1, v1.y, acc2.y);
        acc2.z = fmaf(d1, v1.z, acc2.z); acc2.w = fmaf(d1, v1.w, acc2.w);
    }
    if (i < e) {
        int s0 = srcs[i];
        float d0 = dis[s0];
        float4 v0 = Xv[(size_t)s0 * CH4 + c4];
        acc.x = fmaf(d0, v0.x, acc.x); acc.y = fmaf(d0, v0.y, acc.y);
        acc.z = fmaf(d0, v0.z, acc.z); acc.w = fmaf(d0, v0.w, acc.w);
    }
    float r[4];
    r[0] = dn * (acc.x + acc2.x); r[1] = dn * (acc.y + acc2.y);
    r[2] = dn * (acc.z + acc2.z); r[3] = dn * (acc.w + acc2.w);
    ushort4 hv, lv;
    unsigned short* hp = (unsigned short*)&hv;
    unsigned short* lp = (unsigned short*)&lv;
    #pragma unroll
    for (int c = 0; c < 4; ++c) {
        unsigned hb = bf16_rne_bits(r[c]);
        float hf = __uint_as_float(hb << 16);
        hp[c] = (unsigned short)hb;
        lp[c] = (unsigned short)bf16_rne_bits(r[c] - hf);
    }
    size_t o = (size_t)node * (CH4 * 4) + (size_t)c4 * 4;
    *(ushort4*)&Ahi[o] = hv;
    *(ushort4*)&Alo[o] = lv;
}

// ---------------- GEMM: H[m,n] = relu( sum_k A[m,k] B[k,n] + bias[n] ) ------
// A as bf16 hi/lo [M][K]; B as transposed bf16 hi/lo [N][K]. 3-pass MFMA.
// 128x128 block tile, BK=32, 4 waves each computing 64x64 (4x4 of 16x16x32).

template<int K>
__global__ __launch_bounds__(256) void gemm_mfma_kernel(
    const unsigned short* __restrict__ Ahi, const unsigned short* __restrict__ Alo,
    const unsigned short* __restrict__ Bhi, const unsigned short* __restrict__ Blo,
    const float* __restrict__ bias, float* __restrict__ H, int M) {
    constexpr int BM = 128, BN = 128, BK = 32, LST = 40;  // LDS stride 40 -> 2-way (free)
    __shared__ unsigned short AsHi[BM * LST], AsLo[BM * LST];
    __shared__ unsigned short BsHi[BN * LST], BsLo[BN * LST];
    int tid = threadIdx.x;
    int m0 = blockIdx.y * BM, n0 = blockIdx.x * BN;
    int wid = tid >> 6, lane = tid & 63;
    int wm = (wid & 1) * 64, wn = (wid >> 1) * 64;
    int l16 = lane & 15, quad = lane >> 4;

    f32x4 acc[4][4] = {};

    for (int k0 = 0; k0 < K; k0 += BK) {
        #pragma unroll
        for (int rep = 0; rep < 2; ++rep) {
            int idx = tid + rep * 256;
            int r = idx >> 2, seg = idx & 3;
            int gr = m0 + r;
            uint4 vh = make_uint4(0, 0, 0, 0), vl = make_uint4(0, 0, 0, 0);
            if (gr < M) {
                vh = *(const uint4*)&Ahi[(size_t)gr * K + k0 + seg * 8];
                vl = *(const uint4*)&Alo[(size_t)gr * K + k0 + seg * 8];
            }
            *(uint4*)&AsHi[r * LST + seg * 8] = vh;
            *(uint4*)&AsLo[r * LST + seg * 8] = vl;
            uint4 wh = *(const uint4*)&Bhi[(size_t)(n0 + r) * K + k0 + seg * 8];
            uint4 wl = *(const uint4*)&Blo[(size_t)(n0 + r) * K + k0 + seg * 8];
            *(uint4*)&BsHi[r * LST + seg * 8] = wh;
            *(uint4*)&BsLo[r * LST + seg * 8] = wl;
        }
        __syncthreads();
        bf16x8 bh[4], bl[4];
        #pragma unroll
        for (int ni = 0; ni < 4; ++ni) {
            int n = wn + ni * 16 + l16;
            bh[ni] = *(const bf16x8*)&BsHi[n * LST + quad * 8];
            bl[ni] = *(const bf16x8*)&BsLo[n * LST + quad * 8];
        }
        #pragma unroll
        for (int mi = 0; mi < 4; ++mi) {
            int m = wm + mi * 16 + l16;
            bf16x8 ah = *(const bf16x8*)&AsHi[m * LST + quad * 8];
            bf16x8 al = *(const bf16x8*)&AsLo[m * LST + quad * 8];
            #pragma unroll
            for (int ni = 0; ni < 4; ++ni) {
                acc[mi][ni] = __builtin_amdgcn_mfma_f32_16x16x32_bf16(ah, bh[ni], acc[mi][ni], 0, 0, 0);
                acc[mi][ni] = __builtin_amdgcn_mfma_f32_16x16x32_bf16(ah, bl[ni], acc[mi][ni], 0, 0, 0);
                acc[mi][ni] = __builtin_amdgcn_mfma_f32_16x16x32_bf16(al, bh[ni], acc[mi][ni], 0, 0, 0);
            }
        }
        __syncthreads();
    }
    #pragma unroll
    for (int mi = 0; mi < 4; ++mi) {
        #pragma unroll
        for (int ni = 0; ni < 4; ++ni) {
            int col = n0 + wn + ni * 16 + l16;
            float bv = bias[col];
            #pragma unroll
            for (int r = 0; r < 4; ++r) {
                int grow = m0 + wm + mi * 16 + quad * 4 + r;
                if (grow < M) {
                    float v = acc[mi][ni][r] + bv;
                    H[(size_t)grow * 256 + col] = fmaxf(v, 0.f);
                }
            }
        }
    }
}

// ---------------- mean pool per graph (batch sorted -> contiguous ranges) ----

__global__ __launch_bounds__(256) void pool_kernel(
    const float* __restrict__ H, const int* __restrict__ goff,
    float* __restrict__ pooled) {
    int g = blockIdx.x;
    int t = threadIdx.x;
    int s = goff[g], e = goff[g + 1];
    float acc = 0.f;
    for (int n = s; n < e; ++n) acc += H[(size_t)n * 256 + t];
    float cnt = (float)(e - s);
    pooled[g * 256 + t] = acc / fmaxf(cnt, 1.f);
}

// ---------------- FFN: relu(pooled@Wf+bf) @ Wo + bo,  one block per graph ----

__global__ __launch_bounds__(256) void ffn_kernel(
    const float* __restrict__ pooled, const float* __restrict__ Wf,
    const float* __restrict__ bf, const float* __restrict__ Wo,
    const float* __restrict__ bo, float* __restrict__ out) {
    __shared__ float p[256];
    __shared__ float red[256];
    int g = blockIdx.x, t = threadIdx.x;
    p[t] = pooled[g * 256 + t];
    __syncthreads();
    float s = bf[t];
    for (int k = 0; k < 256; ++k) s = fmaf(p[k], Wf[k * 256 + t], s);
    float gv = fmaxf(s, 0.f);
    red[t] = gv * Wo[t];
    __syncthreads();
    for (int o = 128; o > 0; o >>= 1) {
        if (t < o) red[t] += red[t + o];
        __syncthreads();
    }
    if (t == 0) out[g] = red[0] + bo[0];
}

// ---------------------------------------------------------------------------

extern "C" void kernel_launch(void* const* d_in, const int* in_sizes, int n_in,
                              void* d_out, int out_size, void* d_ws, size_t ws_size,
                              hipStream_t stream) {
    const float* x   = (const float*)d_in[0];
    const int*   ei  = (const int*)d_in[1];
    const int*   bat = (const int*)d_in[2];
    const float* W1  = (const float*)d_in[3];
    const float* b1  = (const float*)d_in[4];
    const float* W2  = (const float*)d_in[5];
    const float* b2  = (const float*)d_in[6];
    const float* W3  = (const float*)d_in[7];
    const float* b3  = (const float*)d_in[8];
    const float* Wf  = (const float*)d_in[9];
    const float* bf  = (const float*)d_in[10];
    const float* Wo  = (const float*)d_in[11];
    const float* bo  = (const float*)d_in[12];
    float* out = (float*)d_out;

    const int N  = in_sizes[2];        // 50000
    const int E  = in_sizes[1] / 2;    // 800000
    const int IC = in_sizes[0] / N;    // 128
    const int HID = 256;
    const int G  = out_size;           // 256
    const int* row = ei;
    const int* col = ei + E;

    char* w = (char*)d_ws;
    size_t off = 0;
    auto alloc = [&](size_t bytes) -> void* {
        void* p = w + off;
        off += (bytes + 255) & ~(size_t)255;
        return p;
    };
    int*   deg    = (int*)alloc((size_t)N * 4);
    float* dis    = (float*)alloc((size_t)N * 4);
    int*   offs   = (int*)alloc((size_t)(N + 1) * 4);
    int*   srcs   = (int*)alloc((size_t)E * 4);
    int*   gcnt   = (int*)alloc((size_t)G * 4);
    int*   goff   = (int*)alloc((size_t)(G + 1) * 4);
    unsigned short* W1hi = (unsigned short*)alloc((size_t)HID * IC * 2);
    unsigned short* W1lo = (unsigned short*)alloc((size_t)HID * IC * 2);
    unsigned short* W2hi = (unsigned short*)alloc((size_t)HID * HID * 2);
    unsigned short* W2lo = (unsigned short*)alloc((size_t)HID * HID * 2);
    unsigned short* W3hi = (unsigned short*)alloc((size_t)HID * HID * 2);
    unsigned short* W3lo = (unsigned short*)alloc((size_t)HID * HID * 2);
    unsigned short* Ahi  = (unsigned short*)alloc((size_t)N * HID * 2);
    unsigned short* Alo  = (unsigned short*)alloc((size_t)N * HID * 2);
    float* Hbuf   = (float*)alloc((size_t)N * HID * 4);
    float* pooled = (float*)alloc((size_t)G * HID * 4);
    (void)ws_size; (void)n_in;

    hipMemsetAsync(deg,  0, (size_t)N * 4, stream);
    hipMemsetAsync(gcnt, 0, (size_t)G * 4, stream);

    degree_kernel<<<(E + THREADS - 1) / THREADS, THREADS, 0, stream>>>(col, deg, E);
    dis_kernel<<<(N + THREADS - 1) / THREADS, THREADS, 0, stream>>>(deg, dis, N);
    exscan_kernel<<<1, THREADS, 0, stream>>>(deg, offs, N);
    csr_fill_kernel<<<(E + THREADS - 1) / THREADS, THREADS, 0, stream>>>(row, col, offs, deg, srcs, E);
    gcount_kernel<<<(N + THREADS - 1) / THREADS, THREADS, 0, stream>>>(bat, gcnt, N);
    exscan_kernel<<<1, THREADS, 0, stream>>>(gcnt, goff, G);

    wsplit_kernel<<<(IC * HID + THREADS - 1) / THREADS, THREADS, 0, stream>>>(W1, W1hi, W1lo, IC, HID);
    wsplit_kernel<<<(HID * HID + THREADS - 1) / THREADS, THREADS, 0, stream>>>(W2, W2hi, W2lo, HID, HID);
    wsplit_kernel<<<(HID * HID + THREADS - 1) / THREADS, THREADS, 0, stream>>>(W3, W3hi, W3lo, HID, HID);

    dim3 ggrid(HID / 128, (N + 127) / 128);
    dim3 agrid1((N + 63) / 64, IC / 16);      // 128 ch -> 8 chunk slices
    dim3 agrid((N + 63) / 64, HID / 16);      // 256 ch -> 16 chunk slices
    // layer 1
    aggregate_chunk_kernel<32><<<agrid1, 256, 0, stream>>>(x, offs, srcs, dis, Ahi, Alo, N);
    gemm_mfma_kernel<128><<<ggrid, 256, 0, stream>>>(Ahi, Alo, W1hi, W1lo, b1, Hbuf, N);
    // layer 2
    aggregate_chunk_kernel<64><<<agrid, 256, 0, stream>>>(Hbuf, offs, srcs, dis, Ahi, Alo, N);
    gemm_mfma_kernel<256><<<ggrid, 256, 0, stream>>>(Ahi, Alo, W2hi, W2lo, b2, Hbuf, N);
    // layer 3
    aggregate_chunk_kernel<64><<<agrid, 256, 0, stream>>>(Hbuf, offs, srcs, dis, Ahi, Alo, N);
    gemm_mfma_kernel<256><<<ggrid, 256, 0, stream>>>(Ahi, Alo, W3hi, W3lo, b3, Hbuf, N);

    pool_kernel<<<G, 256, 0, stream>>>(Hbuf, goff, pooled);
    ffn_kernel<<<G, 256, 0, stream>>>(pooled, Wf, bf, Wo, bo, out);
}

// Round 4
// 589.586 us; speedup vs baseline: 1.6516x; 1.6516x over previous
//
#include <hip/hip_runtime.h>
#include <hip/hip_bf16.h>
#include <hip/hip_fp16.h>

// ---------------------------------------------------------------------------
// GCN forward:  per layer  h' = ReLU( (Â h) @ W + b ),  aggregate-first.
// Node features stored fp16 (halves gather bytes — the dominant cost; random
// gather over 25.6/12.8 MB). Aggregation accumulates in fp32, writes fp16 A.
// GEMM: single-pass fp16 MFMA (16x16x32), fp32 accum, bias+ReLU epilogue,
// fp16 output. Precision: ~3 x 2^-11 roundings/layer, mean-pool + fp32 FFN
// shrink node-level error ~10x -> ~1e-4 << 6.5e-4 threshold.
// CSR built on-device each launch; no atomics in per-channel hot paths.
// ---------------------------------------------------------------------------

#define THREADS 256

typedef _Float16 f16x8 __attribute__((ext_vector_type(8)));
typedef float    f32x4 __attribute__((ext_vector_type(4)));

// ---------------- small setup kernels ----------------

__global__ void degree_kernel(const int* __restrict__ col, int* __restrict__ deg, int E) {
    int e = blockIdx.x * THREADS + threadIdx.x;
    if (e < E) atomicAdd(&deg[col[e]], 1);
}

__global__ void dis_kernel(const int* __restrict__ deg, float* __restrict__ dis, int N) {
    int i = blockIdx.x * THREADS + threadIdx.x;
    if (i < N) dis[i] = rsqrtf((float)(deg[i] + 1));   // +1 self-loop
}

// single-block exclusive scan, 4 elements/thread/iter. out has n+1 slots.
__global__ void exscan_kernel(const int* __restrict__ in, int* __restrict__ out, int n) {
    __shared__ int wsum[4];
    __shared__ int carry_s;
    if (threadIdx.x == 0) carry_s = 0;
    __syncthreads();
    int lane = threadIdx.x & 63, wid = threadIdx.x >> 6;
    for (int base = 0; base < n; base += THREADS * 4) {
        int i0 = base + threadIdx.x * 4;
        int v0 = 0, v1 = 0, v2 = 0, v3 = 0;
        if (i0 + 3 < n) {
            int4 v = *(const int4*)&in[i0];
            v0 = v.x; v1 = v.y; v2 = v.z; v3 = v.w;
        } else {
            if (i0 + 0 < n) v0 = in[i0 + 0];
            if (i0 + 1 < n) v1 = in[i0 + 1];
            if (i0 + 2 < n) v2 = in[i0 + 2];
            if (i0 + 3 < n) v3 = in[i0 + 3];
        }
        int s = v0 + v1 + v2 + v3;
        int inc = s;
        #pragma unroll
        for (int d = 1; d < 64; d <<= 1) {
            int t = __shfl_up(inc, d);
            if (lane >= d) inc += t;
        }
        if (lane == 63) wsum[wid] = inc;
        __syncthreads();
        int add = carry_s;
        for (int w = 0; w < wid; ++w) add += wsum[w];
        int ex = add + inc - s;
        if (i0 + 0 < n) out[i0 + 0] = ex;
        if (i0 + 1 < n) out[i0 + 1] = ex + v0;
        if (i0 + 2 < n) out[i0 + 2] = ex + v0 + v1;
        if (i0 + 3 < n) out[i0 + 3] = ex + v0 + v1 + v2;
        __syncthreads();
        if (threadIdx.x == 0) carry_s += wsum[0] + wsum[1] + wsum[2] + wsum[3];
        __syncthreads();
    }
    if (threadIdx.x == 0) out[n] = carry_s;
}

// uses deg as the countdown (deg no longer needed after dis_kernel)
__global__ void csr_fill_kernel(const int* __restrict__ row, const int* __restrict__ col,
                                const int* __restrict__ offs, int* __restrict__ deg,
                                int* __restrict__ srcs, int E) {
    int e = blockIdx.x * THREADS + threadIdx.x;
    if (e < E) {
        int c = col[e];
        int old = atomicSub(&deg[c], 1);
        srcs[offs[c] + old - 1] = row[e];
    }
}

__global__ void gcount_kernel(const int* __restrict__ batch, int* __restrict__ gcnt, int N) {
    int i = blockIdx.x * THREADS + threadIdx.x;
    if (i < N) atomicAdd(&gcnt[batch[i]], 1);
}

// x fp32 -> fp16, 8 elems/thread
__global__ void xcvt_kernel(const float* __restrict__ X, _Float16* __restrict__ Xh, int total8) {
    int i = blockIdx.x * THREADS + threadIdx.x;
    if (i >= total8) return;
    float4 a = *(const float4*)&X[i * 8];
    float4 b = *(const float4*)&X[i * 8 + 4];
    f16x8 o;
    o[0] = (_Float16)a.x; o[1] = (_Float16)a.y; o[2] = (_Float16)a.z; o[3] = (_Float16)a.w;
    o[4] = (_Float16)b.x; o[5] = (_Float16)b.y; o[6] = (_Float16)b.z; o[7] = (_Float16)b.w;
    *(f16x8*)&Xh[i * 8] = o;
}

// W[K,N] fp32 -> transposed fp16  T[N][K]
__global__ void wcvt_kernel(const float* __restrict__ W, _Float16* __restrict__ T, int K, int Nc) {
    int i = blockIdx.x * THREADS + threadIdx.x;
    if (i >= K * Nc) return;
    int k = i / Nc, n = i % Nc;
    T[n * K + k] = (_Float16)W[i];
}

// ---- aggregation: a[i] = dis[i]*(dis[i]*x[i] + sum_{s in nbr} dis[s]*x[s]) --
// LPN lanes/node, each lane owns 8 fp16 channels (16B gather per lane).
// fp32 accumulate, fp16 output (A operand of the following GEMM).

template<int LPN>   // lanes per node = CH/8  (16 for 128ch, 32 for 256ch)
__global__ __launch_bounds__(256) void aggregate_f16_kernel(
    const _Float16* __restrict__ X, const int* __restrict__ offs,
    const int* __restrict__ srcs, const float* __restrict__ dis,
    _Float16* __restrict__ A, int N) {
    constexpr int NPB = 256 / LPN;
    int node = blockIdx.x * NPB + threadIdx.x / LPN;
    if (node >= N) return;
    int lane = threadIdx.x % LPN;
    const f16x8* Xv = (const f16x8*)X;
    float dn = dis[node];
    f16x8 self = Xv[(size_t)node * LPN + lane];
    float acc[8], acc2[8];
    #pragma unroll
    for (int j = 0; j < 8; ++j) { acc[j] = dn * (float)self[j]; acc2[j] = 0.f; }
    int s = offs[node], e = offs[node + 1];
    int i = s;
    for (; i + 2 <= e; i += 2) {
        int s0 = srcs[i], s1 = srcs[i + 1];
        float d0 = dis[s0], d1 = dis[s1];
        f16x8 v0 = Xv[(size_t)s0 * LPN + lane];
        f16x8 v1 = Xv[(size_t)s1 * LPN + lane];
        #pragma unroll
        for (int j = 0; j < 8; ++j) {
            acc[j]  = fmaf(d0, (float)v0[j], acc[j]);
            acc2[j] = fmaf(d1, (float)v1[j], acc2[j]);
        }
    }
    if (i < e) {
        int s0 = srcs[i];
        float d0 = dis[s0];
        f16x8 v0 = Xv[(size_t)s0 * LPN + lane];
        #pragma unroll
        for (int j = 0; j < 8; ++j) acc[j] = fmaf(d0, (float)v0[j], acc[j]);
    }
    f16x8 o;
    #pragma unroll
    for (int j = 0; j < 8; ++j) o[j] = (_Float16)(dn * (acc[j] + acc2[j]));
    ((f16x8*)A)[(size_t)node * LPN + lane] = o;
}

// ---------------- GEMM: H[m,n] = relu( sum_k A[m,k] B[k,n] + bias[n] ) ------
// A fp16 [M][K]; B transposed fp16 [N][K]. Single-pass 16x16x32 f16 MFMA.
// 128x128 block tile, BK=32, 4 waves each computing 64x64 (4x4 micro-tiles).

template<int K>
__global__ __launch_bounds__(256) void gemm_f16_kernel(
    const _Float16* __restrict__ A, const _Float16* __restrict__ B,
    const float* __restrict__ bias, _Float16* __restrict__ H, int M) {
    constexpr int BM = 128, BN = 128, LST = 40;  // LDS stride 40 halves -> 2-way (free)
    __shared__ _Float16 As[BM * LST];
    __shared__ _Float16 Bs[BN * LST];
    int tid = threadIdx.x;
    int m0 = blockIdx.y * BM, n0 = blockIdx.x * BN;
    int wid = tid >> 6, lane = tid & 63;
    int wm = (wid & 1) * 64, wn = (wid >> 1) * 64;
    int l16 = lane & 15, quad = lane >> 4;

    f32x4 acc[4][4] = {};

    for (int k0 = 0; k0 < K; k0 += 32) {
        #pragma unroll
        for (int rep = 0; rep < 2; ++rep) {
            int idx = tid + rep * 256;
            int r = idx >> 2, seg = idx & 3;
            int gr = m0 + r;
            uint4 va = make_uint4(0, 0, 0, 0);
            if (gr < M) va = *(const uint4*)&A[(size_t)gr * K + k0 + seg * 8];
            *(uint4*)&As[r * LST + seg * 8] = va;
            uint4 vb = *(const uint4*)&B[(size_t)(n0 + r) * K + k0 + seg * 8];
            *(uint4*)&Bs[r * LST + seg * 8] = vb;
        }
        __syncthreads();
        f16x8 bh[4];
        #pragma unroll
        for (int ni = 0; ni < 4; ++ni) {
            int n = wn + ni * 16 + l16;
            bh[ni] = *(const f16x8*)&Bs[n * LST + quad * 8];
        }
        #pragma unroll
        for (int mi = 0; mi < 4; ++mi) {
            int m = wm + mi * 16 + l16;
            f16x8 ah = *(const f16x8*)&As[m * LST + quad * 8];
            #pragma unroll
            for (int ni = 0; ni < 4; ++ni) {
                acc[mi][ni] = __builtin_amdgcn_mfma_f32_16x16x32_f16(ah, bh[ni], acc[mi][ni], 0, 0, 0);
            }
        }
        __syncthreads();
    }
    #pragma unroll
    for (int mi = 0; mi < 4; ++mi) {
        #pragma unroll
        for (int ni = 0; ni < 4; ++ni) {
            int col = n0 + wn + ni * 16 + l16;
            float bv = bias[col];
            #pragma unroll
            for (int r = 0; r < 4; ++r) {
                int grow = m0 + wm + mi * 16 + quad * 4 + r;
                if (grow < M) {
                    float v = fmaxf(acc[mi][ni][r] + bv, 0.f);
                    H[(size_t)grow * 256 + col] = (_Float16)v;
                }
            }
        }
    }
}

// ---------------- mean pool per graph (batch sorted -> contiguous ranges) ----

__global__ __launch_bounds__(256) void pool_kernel(
    const _Float16* __restrict__ H, const int* __restrict__ goff,
    float* __restrict__ pooled) {
    int g = blockIdx.x;
    int t = threadIdx.x;
    int s = goff[g], e = goff[g + 1];
    float acc = 0.f;
    for (int n = s; n < e; ++n) acc += (float)H[(size_t)n * 256 + t];
    float cnt = (float)(e - s);
    pooled[g * 256 + t] = acc / fmaxf(cnt, 1.f);
}

// ---------------- FFN: relu(pooled@Wf+bf) @ Wo + bo,  one block per graph ----

__global__ __launch_bounds__(256) void ffn_kernel(
    const float* __restrict__ pooled, const float* __restrict__ Wf,
    const float* __restrict__ bf, const float* __restrict__ Wo,
    const float* __restrict__ bo, float* __restrict__ out) {
    __shared__ float p[256];
    __shared__ float red[256];
    int g = blockIdx.x, t = threadIdx.x;
    p[t] = pooled[g * 256 + t];
    __syncthreads();
    float s = bf[t];
    for (int k = 0; k < 256; ++k) s = fmaf(p[k], Wf[k * 256 + t], s);
    float gv = fmaxf(s, 0.f);
    red[t] = gv * Wo[t];
    __syncthreads();
    for (int o = 128; o > 0; o >>= 1) {
        if (t < o) red[t] += red[t + o];
        __syncthreads();
    }
    if (t == 0) out[g] = red[0] + bo[0];
}

// ---------------------------------------------------------------------------

extern "C" void kernel_launch(void* const* d_in, const int* in_sizes, int n_in,
                              void* d_out, int out_size, void* d_ws, size_t ws_size,
                              hipStream_t stream) {
    const float* x   = (const float*)d_in[0];
    const int*   ei  = (const int*)d_in[1];
    const int*   bat = (const int*)d_in[2];
    const float* W1  = (const float*)d_in[3];
    const float* b1  = (const float*)d_in[4];
    const float* W2  = (const float*)d_in[5];
    const float* b2  = (const float*)d_in[6];
    const float* W3  = (const float*)d_in[7];
    const float* b3  = (const float*)d_in[8];
    const float* Wf  = (const float*)d_in[9];
    const float* bf  = (const float*)d_in[10];
    const float* Wo  = (const float*)d_in[11];
    const float* bo  = (const float*)d_in[12];
    float* out = (float*)d_out;

    const int N  = in_sizes[2];        // 50000
    const int E  = in_sizes[1] / 2;    // 800000
    const int IC = in_sizes[0] / N;    // 128
    const int HID = 256;
    const int G  = out_size;           // 256
    const int* row = ei;
    const int* col = ei + E;

    char* w = (char*)d_ws;
    size_t off = 0;
    auto alloc = [&](size_t bytes) -> void* {
        void* p = w + off;
        off += (bytes + 255) & ~(size_t)255;
        return p;
    };
    int*   deg    = (int*)alloc((size_t)N * 4);
    float* dis    = (float*)alloc((size_t)N * 4);
    int*   offs   = (int*)alloc((size_t)(N + 1) * 4);
    int*   srcs   = (int*)alloc((size_t)E * 4);
    int*   gcnt   = (int*)alloc((size_t)G * 4);
    int*   goff   = (int*)alloc((size_t)(G + 1) * 4);
    _Float16* W1t = (_Float16*)alloc((size_t)HID * IC * 2);
    _Float16* W2t = (_Float16*)alloc((size_t)HID * HID * 2);
    _Float16* W3t = (_Float16*)alloc((size_t)HID * HID * 2);
    _Float16* Xh  = (_Float16*)alloc((size_t)N * IC * 2);
    _Float16* Ah  = (_Float16*)alloc((size_t)N * HID * 2);
    _Float16* Hh  = (_Float16*)alloc((size_t)N * HID * 2);
    float* pooled = (float*)alloc((size_t)G * HID * 4);
    (void)ws_size; (void)n_in;

    hipMemsetAsync(deg,  0, (size_t)N * 4, stream);
    hipMemsetAsync(gcnt, 0, (size_t)G * 4, stream);

    degree_kernel<<<(E + THREADS - 1) / THREADS, THREADS, 0, stream>>>(col, deg, E);
    dis_kernel<<<(N + THREADS - 1) / THREADS, THREADS, 0, stream>>>(deg, dis, N);
    exscan_kernel<<<1, THREADS, 0, stream>>>(deg, offs, N);
    csr_fill_kernel<<<(E + THREADS - 1) / THREADS, THREADS, 0, stream>>>(row, col, offs, deg, srcs, E);
    gcount_kernel<<<(N + THREADS - 1) / THREADS, THREADS, 0, stream>>>(bat, gcnt, N);
    exscan_kernel<<<1, THREADS, 0, stream>>>(gcnt, goff, G);

    int total8 = N * IC / 8;
    xcvt_kernel<<<(total8 + THREADS - 1) / THREADS, THREADS, 0, stream>>>(x, Xh, total8);
    wcvt_kernel<<<(IC * HID + THREADS - 1) / THREADS, THREADS, 0, stream>>>(W1, W1t, IC, HID);
    wcvt_kernel<<<(HID * HID + THREADS - 1) / THREADS, THREADS, 0, stream>>>(W2, W2t, HID, HID);
    wcvt_kernel<<<(HID * HID + THREADS - 1) / THREADS, THREADS, 0, stream>>>(W3, W3t, HID, HID);

    dim3 ggrid(HID / 128, (N + 127) / 128);
    // layer 1 (128 ch: 16 lanes/node)
    aggregate_f16_kernel<16><<<(N + 15) / 16, 256, 0, stream>>>(Xh, offs, srcs, dis, Ah, N);
    gemm_f16_kernel<128><<<ggrid, 256, 0, stream>>>(Ah, W1t, b1, Hh, N);
    // layer 2 (256 ch: 32 lanes/node)
    aggregate_f16_kernel<32><<<(N + 7) / 8, 256, 0, stream>>>(Hh, offs, srcs, dis, Ah, N);
    gemm_f16_kernel<256><<<ggrid, 256, 0, stream>>>(Ah, W2t, b2, Hh, N);
    // layer 3
    aggregate_f16_kernel<32><<<(N + 7) / 8, 256, 0, stream>>>(Hh, offs, srcs, dis, Ah, N);
    gemm_f16_kernel<256><<<ggrid, 256, 0, stream>>>(Ah, W3t, b3, Hh, N);

    pool_kernel<<<G, 256, 0, stream>>>(Hh, goff, pooled);
    ffn_kernel<<<G, 256, 0, stream>>>(pooled, Wf, bf, Wo, bo, out);
}

// Round 5
// 530.158 us; speedup vs baseline: 1.8368x; 1.1121x over previous
//
#include <hip/hip_runtime.h>
#include <hip/hip_bf16.h>
#include <hip/hip_fp16.h>

// ---------------------------------------------------------------------------
// GCN forward:  per layer  h' = ReLU( (Â h) @ W + b ),  aggregate-first.
// Node features stored fp16 PRE-SCALED by dis[i]:  hs[i] = dis[i]*h[i]
//   -> aggregation is a pure gather-SUM: a[i] = dis[i]*(hs[i] + sum hs[s])
//      (no per-edge dis load, shorter dep chain). GEMM epilogue writes the
//      next layer's pre-scaled input directly; layer 3 writes plain h for
//      pooling. batch is sorted -> graph offsets via boundary detection
//      (no atomics; replaces the 63 us gcount histogram).
// GEMM: single-pass fp16 MFMA 16x16x32, fp32 accum, bias+ReLU epilogue.
// ---------------------------------------------------------------------------

#define THREADS 256

typedef _Float16 f16x8 __attribute__((ext_vector_type(8)));
typedef float    f32x4 __attribute__((ext_vector_type(4)));

// ---------------- small setup kernels ----------------

__global__ void degree_kernel(const int* __restrict__ col, int* __restrict__ deg, int E) {
    int e = blockIdx.x * THREADS + threadIdx.x;
    if (e < E) atomicAdd(&deg[col[e]], 1);
}

__global__ void dis_kernel(const int* __restrict__ deg, float* __restrict__ dis, int N) {
    int i = blockIdx.x * THREADS + threadIdx.x;
    if (i < N) dis[i] = rsqrtf((float)(deg[i] + 1));   // +1 self-loop
}

// single-block exclusive scan, 4 elements/thread/iter. out has n+1 slots.
__global__ void exscan_kernel(const int* __restrict__ in, int* __restrict__ out, int n) {
    __shared__ int wsum[4];
    __shared__ int carry_s;
    if (threadIdx.x == 0) carry_s = 0;
    __syncthreads();
    int lane = threadIdx.x & 63, wid = threadIdx.x >> 6;
    for (int base = 0; base < n; base += THREADS * 4) {
        int i0 = base + threadIdx.x * 4;
        int v0 = 0, v1 = 0, v2 = 0, v3 = 0;
        if (i0 + 3 < n) {
            int4 v = *(const int4*)&in[i0];
            v0 = v.x; v1 = v.y; v2 = v.z; v3 = v.w;
        } else {
            if (i0 + 0 < n) v0 = in[i0 + 0];
            if (i0 + 1 < n) v1 = in[i0 + 1];
            if (i0 + 2 < n) v2 = in[i0 + 2];
            if (i0 + 3 < n) v3 = in[i0 + 3];
        }
        int s = v0 + v1 + v2 + v3;
        int inc = s;
        #pragma unroll
        for (int d = 1; d < 64; d <<= 1) {
            int t = __shfl_up(inc, d);
            if (lane >= d) inc += t;
        }
        if (lane == 63) wsum[wid] = inc;
        __syncthreads();
        int add = carry_s;
        for (int w = 0; w < wid; ++w) add += wsum[w];
        int ex = add + inc - s;
        if (i0 + 0 < n) out[i0 + 0] = ex;
        if (i0 + 1 < n) out[i0 + 1] = ex + v0;
        if (i0 + 2 < n) out[i0 + 2] = ex + v0 + v1;
        if (i0 + 3 < n) out[i0 + 3] = ex + v0 + v1 + v2;
        __syncthreads();
        if (threadIdx.x == 0) carry_s += wsum[0] + wsum[1] + wsum[2] + wsum[3];
        __syncthreads();
    }
    if (threadIdx.x == 0) out[n] = carry_s;
}

// uses deg as the countdown (deg no longer needed after dis_kernel)
__global__ void csr_fill_kernel(const int* __restrict__ row, const int* __restrict__ col,
                                const int* __restrict__ offs, int* __restrict__ deg,
                                int* __restrict__ srcs, int E) {
    int e = blockIdx.x * THREADS + threadIdx.x;
    if (e < E) {
        int c = col[e];
        int old = atomicSub(&deg[c], 1);
        srcs[offs[c] + old - 1] = row[e];
    }
}

// batch sorted -> goff[g] = first node index with batch >= g. No atomics.
__global__ void goff_kernel(const int* __restrict__ batch, int* __restrict__ goff,
                            int N, int G) {
    int i = blockIdx.x * THREADS + threadIdx.x;
    if (i >= N) return;
    int b1 = batch[i];
    int b0 = (i == 0) ? -1 : batch[i - 1];
    for (int g = b0 + 1; g <= b1; ++g) goff[g] = i;
    if (i == N - 1) {
        for (int g = b1 + 1; g <= G; ++g) goff[g] = N;
    }
}

// x fp32 -> fp16 pre-scaled by dis[node], 8 elems/thread
__global__ void xcvt_scale_kernel(const float* __restrict__ X, const float* __restrict__ dis,
                                  _Float16* __restrict__ Xs, int total8, int IC) {
    int i = blockIdx.x * THREADS + threadIdx.x;
    if (i >= total8) return;
    int idx = i * 8;
    float d = dis[idx / IC];
    float4 a = *(const float4*)&X[idx];
    float4 b = *(const float4*)&X[idx + 4];
    f16x8 o;
    o[0] = (_Float16)(d * a.x); o[1] = (_Float16)(d * a.y);
    o[2] = (_Float16)(d * a.z); o[3] = (_Float16)(d * a.w);
    o[4] = (_Float16)(d * b.x); o[5] = (_Float16)(d * b.y);
    o[6] = (_Float16)(d * b.z); o[7] = (_Float16)(d * b.w);
    *(f16x8*)&Xs[idx] = o;
}

// W[K,N] fp32 -> transposed fp16  T[N][K]
__global__ void wcvt_kernel(const float* __restrict__ W, _Float16* __restrict__ T, int K, int Nc) {
    int i = blockIdx.x * THREADS + threadIdx.x;
    if (i >= K * Nc) return;
    int k = i / Nc, n = i % Nc;
    T[n * K + k] = (_Float16)W[i];
}

// ---- aggregation: a[i] = dis[i] * ( hs[i] + sum_{s in nbr} hs[s] ) ----------
// hs is pre-scaled by dis at the producer. LPN lanes/node, 8 fp16 ch/lane.
// Pure gather-sum, fp32 accumulate, 4-way unrolled for loads-in-flight.

template<int LPN>   // lanes per node = CH/8  (16 for 128ch, 32 for 256ch)
__global__ __launch_bounds__(256) void aggregate_f16_kernel(
    const _Float16* __restrict__ X, const int* __restrict__ offs,
    const int* __restrict__ srcs, const float* __restrict__ dis,
    _Float16* __restrict__ A, int N) {
    constexpr int NPB = 256 / LPN;
    int node = blockIdx.x * NPB + threadIdx.x / LPN;
    if (node >= N) return;
    int lane = threadIdx.x % LPN;
    const f16x8* Xv = (const f16x8*)X;
    f16x8 self = Xv[(size_t)node * LPN + lane];
    float acc[8], acc2[8];
    #pragma unroll
    for (int j = 0; j < 8; ++j) { acc[j] = (float)self[j]; acc2[j] = 0.f; }
    int s = offs[node], e = offs[node + 1];
    int i = s;
    for (; i + 4 <= e; i += 4) {
        int s0 = srcs[i], s1 = srcs[i + 1], s2 = srcs[i + 2], s3 = srcs[i + 3];
        f16x8 v0 = Xv[(size_t)s0 * LPN + lane];
        f16x8 v1 = Xv[(size_t)s1 * LPN + lane];
        f16x8 v2 = Xv[(size_t)s2 * LPN + lane];
        f16x8 v3 = Xv[(size_t)s3 * LPN + lane];
        #pragma unroll
        for (int j = 0; j < 8; ++j) {
            acc[j]  += (float)v0[j] + (float)v2[j];
            acc2[j] += (float)v1[j] + (float)v3[j];
        }
    }
    for (; i < e; ++i) {
        int s0 = srcs[i];
        f16x8 v0 = Xv[(size_t)s0 * LPN + lane];
        #pragma unroll
        for (int j = 0; j < 8; ++j) acc[j] += (float)v0[j];
    }
    float dn = dis[node];
    f16x8 o;
    #pragma unroll
    for (int j = 0; j < 8; ++j) o[j] = (_Float16)(dn * (acc[j] + acc2[j]));
    ((f16x8*)A)[(size_t)node * LPN + lane] = o;
}

// ---------------- GEMM: H[m,n] = relu( sum_k A[m,k] B[k,n] + bias[n] ) ------
// A fp16 [M][K]; B transposed fp16 [N][K]. Single-pass 16x16x32 f16 MFMA.
// 128x128 block tile, BK=32, 4 waves each computing 64x64 (4x4 micro-tiles).
// SCALE: multiply output row by dscale[row] (pre-scales the next layer input).

template<int K, bool SCALE>
__global__ __launch_bounds__(256) void gemm_f16_kernel(
    const _Float16* __restrict__ A, const _Float16* __restrict__ B,
    const float* __restrict__ bias, const float* __restrict__ dscale,
    _Float16* __restrict__ H, int M) {
    constexpr int BM = 128, BN = 128, LST = 40;  // LDS stride 40 halves -> 2-way (free)
    __shared__ _Float16 As[BM * LST];
    __shared__ _Float16 Bs[BN * LST];
    int tid = threadIdx.x;
    int m0 = blockIdx.y * BM, n0 = blockIdx.x * BN;
    int wid = tid >> 6, lane = tid & 63;
    int wm = (wid & 1) * 64, wn = (wid >> 1) * 64;
    int l16 = lane & 15, quad = lane >> 4;

    f32x4 acc[4][4] = {};

    for (int k0 = 0; k0 < K; k0 += 32) {
        #pragma unroll
        for (int rep = 0; rep < 2; ++rep) {
            int idx = tid + rep * 256;
            int r = idx >> 2, seg = idx & 3;
            int gr = m0 + r;
            uint4 va = make_uint4(0, 0, 0, 0);
            if (gr < M) va = *(const uint4*)&A[(size_t)gr * K + k0 + seg * 8];
            *(uint4*)&As[r * LST + seg * 8] = va;
            uint4 vb = *(const uint4*)&B[(size_t)(n0 + r) * K + k0 + seg * 8];
            *(uint4*)&Bs[r * LST + seg * 8] = vb;
        }
        __syncthreads();
        f16x8 bh[4];
        #pragma unroll
        for (int ni = 0; ni < 4; ++ni) {
            int n = wn + ni * 16 + l16;
            bh[ni] = *(const f16x8*)&Bs[n * LST + quad * 8];
        }
        #pragma unroll
        for (int mi = 0; mi < 4; ++mi) {
            int m = wm + mi * 16 + l16;
            f16x8 ah = *(const f16x8*)&As[m * LST + quad * 8];
            #pragma unroll
            for (int ni = 0; ni < 4; ++ni) {
                acc[mi][ni] = __builtin_amdgcn_mfma_f32_16x16x32_f16(ah, bh[ni], acc[mi][ni], 0, 0, 0);
            }
        }
        __syncthreads();
    }
    #pragma unroll
    for (int mi = 0; mi < 4; ++mi) {
        #pragma unroll
        for (int ni = 0; ni < 4; ++ni) {
            int col = n0 + wn + ni * 16 + l16;
            float bv = bias[col];
            #pragma unroll
            for (int r = 0; r < 4; ++r) {
                int grow = m0 + wm + mi * 16 + quad * 4 + r;
                if (grow < M) {
                    float v = fmaxf(acc[mi][ni][r] + bv, 0.f);
                    if (SCALE) v *= dscale[grow];
                    H[(size_t)grow * 256 + col] = (_Float16)v;
                }
            }
        }
    }
}

// ---------------- mean pool per graph (batch sorted -> contiguous ranges) ----

__global__ __launch_bounds__(256) void pool_kernel(
    const _Float16* __restrict__ H, const int* __restrict__ goff,
    float* __restrict__ pooled) {
    int g = blockIdx.x;
    int t = threadIdx.x;
    int s = goff[g], e = goff[g + 1];
    float acc = 0.f;
    for (int n = s; n < e; ++n) acc += (float)H[(size_t)n * 256 + t];
    float cnt = (float)(e - s);
    pooled[g * 256 + t] = acc / fmaxf(cnt, 1.f);
}

// ---------------- FFN: relu(pooled@Wf+bf) @ Wo + bo,  one block per graph ----

__global__ __launch_bounds__(256) void ffn_kernel(
    const float* __restrict__ pooled, const float* __restrict__ Wf,
    const float* __restrict__ bf, const float* __restrict__ Wo,
    const float* __restrict__ bo, float* __restrict__ out) {
    __shared__ float p[256];
    __shared__ float red[256];
    int g = blockIdx.x, t = threadIdx.x;
    p[t] = pooled[g * 256 + t];
    __syncthreads();
    float s = bf[t];
    for (int k = 0; k < 256; ++k) s = fmaf(p[k], Wf[k * 256 + t], s);
    float gv = fmaxf(s, 0.f);
    red[t] = gv * Wo[t];
    __syncthreads();
    for (int o = 128; o > 0; o >>= 1) {
        if (t < o) red[t] += red[t + o];
        __syncthreads();
    }
    if (t == 0) out[g] = red[0] + bo[0];
}

// ---------------------------------------------------------------------------

extern "C" void kernel_launch(void* const* d_in, const int* in_sizes, int n_in,
                              void* d_out, int out_size, void* d_ws, size_t ws_size,
                              hipStream_t stream) {
    const float* x   = (const float*)d_in[0];
    const int*   ei  = (const int*)d_in[1];
    const int*   bat = (const int*)d_in[2];
    const float* W1  = (const float*)d_in[3];
    const float* b1  = (const float*)d_in[4];
    const float* W2  = (const float*)d_in[5];
    const float* b2  = (const float*)d_in[6];
    const float* W3  = (const float*)d_in[7];
    const float* b3  = (const float*)d_in[8];
    const float* Wf  = (const float*)d_in[9];
    const float* bf  = (const float*)d_in[10];
    const float* Wo  = (const float*)d_in[11];
    const float* bo  = (const float*)d_in[12];
    float* out = (float*)d_out;

    const int N  = in_sizes[2];        // 50000
    const int E  = in_sizes[1] / 2;    // 800000
    const int IC = in_sizes[0] / N;    // 128
    const int HID = 256;
    const int G  = out_size;           // 256
    const int* row = ei;
    const int* col = ei + E;

    char* w = (char*)d_ws;
    size_t off = 0;
    auto alloc = [&](size_t bytes) -> void* {
        void* p = w + off;
        off += (bytes + 255) & ~(size_t)255;
        return p;
    };
    int*   deg    = (int*)alloc((size_t)N * 4);
    float* dis    = (float*)alloc((size_t)N * 4);
    int*   offs   = (int*)alloc((size_t)(N + 1) * 4);
    int*   srcs   = (int*)alloc((size_t)E * 4);
    int*   goff   = (int*)alloc((size_t)(G + 1) * 4);
    _Float16* W1t = (_Float16*)alloc((size_t)HID * IC * 2);
    _Float16* W2t = (_Float16*)alloc((size_t)HID * HID * 2);
    _Float16* W3t = (_Float16*)alloc((size_t)HID * HID * 2);
    _Float16* Xs  = (_Float16*)alloc((size_t)N * IC * 2);
    _Float16* Ah  = (_Float16*)alloc((size_t)N * HID * 2);
    _Float16* Hs  = (_Float16*)alloc((size_t)N * HID * 2);
    float* pooled = (float*)alloc((size_t)G * HID * 4);
    (void)ws_size; (void)n_in;

    hipMemsetAsync(deg, 0, (size_t)N * 4, stream);

    degree_kernel<<<(E + THREADS - 1) / THREADS, THREADS, 0, stream>>>(col, deg, E);
    dis_kernel<<<(N + THREADS - 1) / THREADS, THREADS, 0, stream>>>(deg, dis, N);
    exscan_kernel<<<1, THREADS, 0, stream>>>(deg, offs, N);
    csr_fill_kernel<<<(E + THREADS - 1) / THREADS, THREADS, 0, stream>>>(row, col, offs, deg, srcs, E);
    goff_kernel<<<(N + THREADS - 1) / THREADS, THREADS, 0, stream>>>(bat, goff, N, G);

    int total8 = N * IC / 8;
    xcvt_scale_kernel<<<(total8 + THREADS - 1) / THREADS, THREADS, 0, stream>>>(x, dis, Xs, total8, IC);
    wcvt_kernel<<<(IC * HID + THREADS - 1) / THREADS, THREADS, 0, stream>>>(W1, W1t, IC, HID);
    wcvt_kernel<<<(HID * HID + THREADS - 1) / THREADS, THREADS, 0, stream>>>(W2, W2t, HID, HID);
    wcvt_kernel<<<(HID * HID + THREADS - 1) / THREADS, THREADS, 0, stream>>>(W3, W3t, HID, HID);

    dim3 ggrid(HID / 128, (N + 127) / 128);
    // layer 1 (128 ch: 16 lanes/node); GEMM writes dis-scaled h1
    aggregate_f16_kernel<16><<<(N + 15) / 16, 256, 0, stream>>>(Xs, offs, srcs, dis, Ah, N);
    gemm_f16_kernel<128, true><<<ggrid, 256, 0, stream>>>(Ah, W1t, b1, dis, Hs, N);
    // layer 2 (256 ch: 32 lanes/node); GEMM writes dis-scaled h2
    aggregate_f16_kernel<32><<<(N + 7) / 8, 256, 0, stream>>>(Hs, offs, srcs, dis, Ah, N);
    gemm_f16_kernel<256, true><<<ggrid, 256, 0, stream>>>(Ah, W2t, b2, dis, Hs, N);
    // layer 3: GEMM writes plain h3 for pooling
    aggregate_f16_kernel<32><<<(N + 7) / 8, 256, 0, stream>>>(Hs, offs, srcs, dis, Ah, N);
    gemm_f16_kernel<256, false><<<ggrid, 256, 0, stream>>>(Ah, W3t, b3, nullptr, Hs, N);

    pool_kernel<<<G, 256, 0, stream>>>(Hs, goff, pooled);
    ffn_kernel<<<G, 256, 0, stream>>>(pooled, Wf, bf, Wo, bo, out);
}

// Round 6
// 459.841 us; speedup vs baseline: 2.1176x; 1.1529x over previous
//
#include <hip/hip_runtime.h>
#include <hip/hip_bf16.h>
#include <hip/hip_fp16.h>

// ---------------------------------------------------------------------------
// GCN forward:  per layer  h' = ReLU( (Â h) @ W + b ),  aggregate-first.
// Node features stored fp16 PRE-SCALED by dis[i]:  hs[i] = dis[i]*h[i]
//   -> aggregation is a pure gather-SUM: a[i] = dis[i]*(hs[i] + sum hs[s])
// GEMM: single-pass fp16 MFMA 16x16x32, fp32 accum, bias+ReLU epilogue.
// R6: multi-block scan (replaces single-block exscan), node-parallel
// segmented pool (replaces per-graph serial pool), degree+goff merged.
// ---------------------------------------------------------------------------

#define THREADS 256

typedef _Float16 f16x8 __attribute__((ext_vector_type(8)));
typedef float    f32x4 __attribute__((ext_vector_type(4)));

// ---------------- setup kernels ----------------

// degree histogram (i<E) + graph offsets from sorted batch (i<N), one launch
__global__ void degree_goff_kernel(const int* __restrict__ col, int* __restrict__ deg, int E,
                                   const int* __restrict__ batch, int* __restrict__ goff,
                                   int N, int G) {
    int i = blockIdx.x * THREADS + threadIdx.x;
    if (i < E) atomicAdd(&deg[col[i]], 1);
    if (i < N) {
        int b1 = batch[i];
        int b0 = (i == 0) ? -1 : batch[i - 1];
        for (int g = b0 + 1; g <= b1; ++g) goff[g] = i;
        if (i == N - 1) {
            for (int g = b1 + 1; g <= G; ++g) goff[g] = N;
        }
    }
}

// scan phase A: per-block (1024 elems) exclusive scan + block sum; also dis.
__global__ __launch_bounds__(256) void scanA_kernel(
    const int* __restrict__ in, int* __restrict__ out, int* __restrict__ bsum,
    float* __restrict__ dis, int n) {
    __shared__ int wsum[4];
    int i0 = blockIdx.x * 1024 + threadIdx.x * 4;
    int lane = threadIdx.x & 63, wid = threadIdx.x >> 6;
    int v0 = 0, v1 = 0, v2 = 0, v3 = 0;
    if (i0 + 3 < n) {
        int4 v = *(const int4*)&in[i0];
        v0 = v.x; v1 = v.y; v2 = v.z; v3 = v.w;
    } else {
        if (i0 + 0 < n) v0 = in[i0 + 0];
        if (i0 + 1 < n) v1 = in[i0 + 1];
        if (i0 + 2 < n) v2 = in[i0 + 2];
        if (i0 + 3 < n) v3 = in[i0 + 3];
    }
    // dis = rsqrt(deg+1) folded in (in == deg)
    if (i0 + 0 < n) dis[i0 + 0] = rsqrtf((float)(v0 + 1));
    if (i0 + 1 < n) dis[i0 + 1] = rsqrtf((float)(v1 + 1));
    if (i0 + 2 < n) dis[i0 + 2] = rsqrtf((float)(v2 + 1));
    if (i0 + 3 < n) dis[i0 + 3] = rsqrtf((float)(v3 + 1));
    int s = v0 + v1 + v2 + v3;
    int inc = s;
    #pragma unroll
    for (int d = 1; d < 64; d <<= 1) {
        int t = __shfl_up(inc, d);
        if (lane >= d) inc += t;
    }
    if (lane == 63) wsum[wid] = inc;
    __syncthreads();
    int add = 0;
    for (int w = 0; w < wid; ++w) add += wsum[w];
    int ex = add + inc - s;
    if (i0 + 0 < n) out[i0 + 0] = ex;
    if (i0 + 1 < n) out[i0 + 1] = ex + v0;
    if (i0 + 2 < n) out[i0 + 2] = ex + v0 + v1;
    if (i0 + 3 < n) out[i0 + 3] = ex + v0 + v1 + v2;
    if (threadIdx.x == 255) bsum[blockIdx.x] = add + inc;  // block total
}

// scan phase B: 1 wave scans <=64 block sums; writes grand total to out[n].
__global__ void scanB_kernel(int* __restrict__ bsum, int* __restrict__ total_slot, int nb) {
    int lane = threadIdx.x;
    int v = (lane < nb) ? bsum[lane] : 0;
    int inc = v;
    #pragma unroll
    for (int d = 1; d < 64; d <<= 1) {
        int t = __shfl_up(inc, d);
        if (lane >= d) inc += t;
    }
    if (lane < nb) bsum[lane] = inc - v;   // exclusive
    if (lane == 63) *total_slot = inc;
}

// scan phase C: add scanned block offsets back.
__global__ void scanC_kernel(int* __restrict__ out, const int* __restrict__ bsum, int n) {
    int i = blockIdx.x * THREADS + threadIdx.x;
    if (i < n) out[i] += bsum[i >> 10];
}

// uses deg as the countdown (deg no longer needed after scanA)
__global__ void csr_fill_kernel(const int* __restrict__ row, const int* __restrict__ col,
                                const int* __restrict__ offs, int* __restrict__ deg,
                                int* __restrict__ srcs, int E) {
    int e = blockIdx.x * THREADS + threadIdx.x;
    if (e < E) {
        int c = col[e];
        int old = atomicSub(&deg[c], 1);
        srcs[offs[c] + old - 1] = row[e];
    }
}

// x fp32 -> fp16 pre-scaled by dis[node], 8 elems/thread
__global__ void xcvt_scale_kernel(const float* __restrict__ X, const float* __restrict__ dis,
                                  _Float16* __restrict__ Xs, int total8, int IC) {
    int i = blockIdx.x * THREADS + threadIdx.x;
    if (i >= total8) return;
    int idx = i * 8;
    float d = dis[idx / IC];
    float4 a = *(const float4*)&X[idx];
    float4 b = *(const float4*)&X[idx + 4];
    f16x8 o;
    o[0] = (_Float16)(d * a.x); o[1] = (_Float16)(d * a.y);
    o[2] = (_Float16)(d * a.z); o[3] = (_Float16)(d * a.w);
    o[4] = (_Float16)(d * b.x); o[5] = (_Float16)(d * b.y);
    o[6] = (_Float16)(d * b.z); o[7] = (_Float16)(d * b.w);
    *(f16x8*)&Xs[idx] = o;
}

// W[K,N] fp32 -> transposed fp16  T[N][K]
__global__ void wcvt_kernel(const float* __restrict__ W, _Float16* __restrict__ T, int K, int Nc) {
    int i = blockIdx.x * THREADS + threadIdx.x;
    if (i >= K * Nc) return;
    int k = i / Nc, n = i % Nc;
    T[n * K + k] = (_Float16)W[i];
}

// ---- aggregation: a[i] = dis[i] * ( hs[i] + sum_{s in nbr} hs[s] ) ----------

template<int LPN>   // lanes per node = CH/8  (16 for 128ch, 32 for 256ch)
__global__ __launch_bounds__(256) void aggregate_f16_kernel(
    const _Float16* __restrict__ X, const int* __restrict__ offs,
    const int* __restrict__ srcs, const float* __restrict__ dis,
    _Float16* __restrict__ A, int N) {
    constexpr int NPB = 256 / LPN;
    int node = blockIdx.x * NPB + threadIdx.x / LPN;
    if (node >= N) return;
    int lane = threadIdx.x % LPN;
    const f16x8* Xv = (const f16x8*)X;
    f16x8 self = Xv[(size_t)node * LPN + lane];
    float acc[8], acc2[8];
    #pragma unroll
    for (int j = 0; j < 8; ++j) { acc[j] = (float)self[j]; acc2[j] = 0.f; }
    int s = offs[node], e = offs[node + 1];
    int i = s;
    for (; i + 4 <= e; i += 4) {
        int s0 = srcs[i], s1 = srcs[i + 1], s2 = srcs[i + 2], s3 = srcs[i + 3];
        f16x8 v0 = Xv[(size_t)s0 * LPN + lane];
        f16x8 v1 = Xv[(size_t)s1 * LPN + lane];
        f16x8 v2 = Xv[(size_t)s2 * LPN + lane];
        f16x8 v3 = Xv[(size_t)s3 * LPN + lane];
        #pragma unroll
        for (int j = 0; j < 8; ++j) {
            acc[j]  += (float)v0[j] + (float)v2[j];
            acc2[j] += (float)v1[j] + (float)v3[j];
        }
    }
    for (; i < e; ++i) {
        int s0 = srcs[i];
        f16x8 v0 = Xv[(size_t)s0 * LPN + lane];
        #pragma unroll
        for (int j = 0; j < 8; ++j) acc[j] += (float)v0[j];
    }
    float dn = dis[node];
    f16x8 o;
    #pragma unroll
    for (int j = 0; j < 8; ++j) o[j] = (_Float16)(dn * (acc[j] + acc2[j]));
    ((f16x8*)A)[(size_t)node * LPN + lane] = o;
}

// ---------------- GEMM: H[m,n] = relu( sum_k A[m,k] B[k,n] + bias[n] ) ------

template<int K, bool SCALE>
__global__ __launch_bounds__(256) void gemm_f16_kernel(
    const _Float16* __restrict__ A, const _Float16* __restrict__ B,
    const float* __restrict__ bias, const float* __restrict__ dscale,
    _Float16* __restrict__ H, int M) {
    constexpr int BM = 128, BN = 128, LST = 40;  // LDS stride 40 halves -> 2-way (free)
    __shared__ _Float16 As[BM * LST];
    __shared__ _Float16 Bs[BN * LST];
    int tid = threadIdx.x;
    int m0 = blockIdx.y * BM, n0 = blockIdx.x * BN;
    int wid = tid >> 6, lane = tid & 63;
    int wm = (wid & 1) * 64, wn = (wid >> 1) * 64;
    int l16 = lane & 15, quad = lane >> 4;

    f32x4 acc[4][4] = {};

    for (int k0 = 0; k0 < K; k0 += 32) {
        #pragma unroll
        for (int rep = 0; rep < 2; ++rep) {
            int idx = tid + rep * 256;
            int r = idx >> 2, seg = idx & 3;
            int gr = m0 + r;
            uint4 va = make_uint4(0, 0, 0, 0);
            if (gr < M) va = *(const uint4*)&A[(size_t)gr * K + k0 + seg * 8];
            *(uint4*)&As[r * LST + seg * 8] = va;
            uint4 vb = *(const uint4*)&B[(size_t)(n0 + r) * K + k0 + seg * 8];
            *(uint4*)&Bs[r * LST + seg * 8] = vb;
        }
        __syncthreads();
        f16x8 bh[4];
        #pragma unroll
        for (int ni = 0; ni < 4; ++ni) {
            int n = wn + ni * 16 + l16;
            bh[ni] = *(const f16x8*)&Bs[n * LST + quad * 8];
        }
        #pragma unroll
        for (int mi = 0; mi < 4; ++mi) {
            int m = wm + mi * 16 + l16;
            f16x8 ah = *(const f16x8*)&As[m * LST + quad * 8];
            #pragma unroll
            for (int ni = 0; ni < 4; ++ni) {
                acc[mi][ni] = __builtin_amdgcn_mfma_f32_16x16x32_f16(ah, bh[ni], acc[mi][ni], 0, 0, 0);
            }
        }
        __syncthreads();
    }
    #pragma unroll
    for (int mi = 0; mi < 4; ++mi) {
        #pragma unroll
        for (int ni = 0; ni < 4; ++ni) {
            int col = n0 + wn + ni * 16 + l16;
            float bv = bias[col];
            #pragma unroll
            for (int r = 0; r < 4; ++r) {
                int grow = m0 + wm + mi * 16 + quad * 4 + r;
                if (grow < M) {
                    float v = fmaxf(acc[mi][ni][r] + bv, 0.f);
                    if (SCALE) v *= dscale[grow];
                    H[(size_t)grow * 256 + col] = (_Float16)v;
                }
            }
        }
    }
}

// ---- node-parallel segmented pool: 64 nodes/block, thread = channel --------
// batch sorted -> per-block run-length segments, one fp32 atomicAdd/segment.

__global__ __launch_bounds__(256) void pool_part_kernel(
    const _Float16* __restrict__ H, const int* __restrict__ batch,
    float* __restrict__ pooled, int N) {
    __shared__ int bsh[64];
    int n0 = blockIdx.x * 64;
    if (threadIdx.x < 64) {
        int n = n0 + threadIdx.x;
        bsh[threadIdx.x] = (n < N) ? batch[n] : -1;
    }
    __syncthreads();
    int c = threadIdx.x;
    int lim = min(64, N - n0);
    if (lim <= 0) return;
    float acc = 0.f;
    int gcur = bsh[0];
    for (int j = 0; j < lim; ++j) {
        int g = bsh[j];               // uniform across block
        if (g != gcur) {
            atomicAdd(&pooled[gcur * 256 + c], acc);
            acc = 0.f; gcur = g;
        }
        acc += (float)H[(size_t)(n0 + j) * 256 + c];
    }
    atomicAdd(&pooled[gcur * 256 + c], acc);
}

// ---------------- FFN: relu(pooled/cnt @Wf+bf) @ Wo + bo, one block/graph ----

__global__ __launch_bounds__(256) void ffn_kernel(
    const float* __restrict__ pooled, const int* __restrict__ goff,
    const float* __restrict__ Wf, const float* __restrict__ bf,
    const float* __restrict__ Wo, const float* __restrict__ bo,
    float* __restrict__ out) {
    __shared__ float p[256];
    __shared__ float red[256];
    int g = blockIdx.x, t = threadIdx.x;
    int cnt = goff[g + 1] - goff[g];
    float inv = 1.f / (float)max(cnt, 1);
    p[t] = pooled[g * 256 + t] * inv;
    __syncthreads();
    float s = bf[t];
    #pragma unroll 8
    for (int k = 0; k < 256; ++k) s = fmaf(p[k], Wf[k * 256 + t], s);
    float gv = fmaxf(s, 0.f);
    red[t] = gv * Wo[t];
    __syncthreads();
    for (int o = 128; o > 0; o >>= 1) {
        if (t < o) red[t] += red[t + o];
        __syncthreads();
    }
    if (t == 0) out[g] = red[0] + bo[0];
}

// ---------------------------------------------------------------------------

extern "C" void kernel_launch(void* const* d_in, const int* in_sizes, int n_in,
                              void* d_out, int out_size, void* d_ws, size_t ws_size,
                              hipStream_t stream) {
    const float* x   = (const float*)d_in[0];
    const int*   ei  = (const int*)d_in[1];
    const int*   bat = (const int*)d_in[2];
    const float* W1  = (const float*)d_in[3];
    const float* b1  = (const float*)d_in[4];
    const float* W2  = (const float*)d_in[5];
    const float* b2  = (const float*)d_in[6];
    const float* W3  = (const float*)d_in[7];
    const float* b3  = (const float*)d_in[8];
    const float* Wf  = (const float*)d_in[9];
    const float* bf  = (const float*)d_in[10];
    const float* Wo  = (const float*)d_in[11];
    const float* bo  = (const float*)d_in[12];
    float* out = (float*)d_out;

    const int N  = in_sizes[2];        // 50000
    const int E  = in_sizes[1] / 2;    // 800000
    const int IC = in_sizes[0] / N;    // 128
    const int HID = 256;
    const int G  = out_size;           // 256
    const int* row = ei;
    const int* col = ei + E;

    char* w = (char*)d_ws;
    size_t off = 0;
    auto alloc = [&](size_t bytes) -> void* {
        void* p = w + off;
        off += (bytes + 255) & ~(size_t)255;
        return p;
    };
    int*   deg    = (int*)alloc((size_t)N * 4);
    float* dis    = (float*)alloc((size_t)N * 4);
    int*   offs   = (int*)alloc((size_t)(N + 1) * 4);
    int*   srcs   = (int*)alloc((size_t)E * 4);
    int*   goff   = (int*)alloc((size_t)(G + 1) * 4);
    int*   bsum   = (int*)alloc((size_t)64 * 4);
    _Float16* W1t = (_Float16*)alloc((size_t)HID * IC * 2);
    _Float16* W2t = (_Float16*)alloc((size_t)HID * HID * 2);
    _Float16* W3t = (_Float16*)alloc((size_t)HID * HID * 2);
    _Float16* Xs  = (_Float16*)alloc((size_t)N * IC * 2);
    _Float16* Ah  = (_Float16*)alloc((size_t)N * HID * 2);
    _Float16* Hs  = (_Float16*)alloc((size_t)N * HID * 2);
    float* pooled = (float*)alloc((size_t)G * HID * 4);
    (void)ws_size; (void)n_in;

    hipMemsetAsync(deg, 0, (size_t)N * 4, stream);
    hipMemsetAsync(pooled, 0, (size_t)G * HID * 4, stream);

    int nb = (N + 1023) / 1024;   // 49 <= 64
    degree_goff_kernel<<<(E + THREADS - 1) / THREADS, THREADS, 0, stream>>>(
        col, deg, E, bat, goff, N, G);
    scanA_kernel<<<nb, 256, 0, stream>>>(deg, offs, bsum, dis, N);
    scanB_kernel<<<1, 64, 0, stream>>>(bsum, &offs[N], nb);
    scanC_kernel<<<(N + THREADS - 1) / THREADS, THREADS, 0, stream>>>(offs, bsum, N);
    csr_fill_kernel<<<(E + THREADS - 1) / THREADS, THREADS, 0, stream>>>(row, col, offs, deg, srcs, E);

    int total8 = N * IC / 8;
    xcvt_scale_kernel<<<(total8 + THREADS - 1) / THREADS, THREADS, 0, stream>>>(x, dis, Xs, total8, IC);
    wcvt_kernel<<<(IC * HID + THREADS - 1) / THREADS, THREADS, 0, stream>>>(W1, W1t, IC, HID);
    wcvt_kernel<<<(HID * HID + THREADS - 1) / THREADS, THREADS, 0, stream>>>(W2, W2t, HID, HID);
    wcvt_kernel<<<(HID * HID + THREADS - 1) / THREADS, THREADS, 0, stream>>>(W3, W3t, HID, HID);

    dim3 ggrid(HID / 128, (N + 127) / 128);
    // layer 1 (128 ch: 16 lanes/node); GEMM writes dis-scaled h1
    aggregate_f16_kernel<16><<<(N + 15) / 16, 256, 0, stream>>>(Xs, offs, srcs, dis, Ah, N);
    gemm_f16_kernel<128, true><<<ggrid, 256, 0, stream>>>(Ah, W1t, b1, dis, Hs, N);
    // layer 2 (256 ch: 32 lanes/node); GEMM writes dis-scaled h2
    aggregate_f16_kernel<32><<<(N + 7) / 8, 256, 0, stream>>>(Hs, offs, srcs, dis, Ah, N);
    gemm_f16_kernel<256, true><<<ggrid, 256, 0, stream>>>(Ah, W2t, b2, dis, Hs, N);
    // layer 3: GEMM writes plain h3 for pooling
    aggregate_f16_kernel<32><<<(N + 7) / 8, 256, 0, stream>>>(Hs, offs, srcs, dis, Ah, N);
    gemm_f16_kernel<256, false><<<ggrid, 256, 0, stream>>>(Ah, W3t, b3, nullptr, Hs, N);

    pool_part_kernel<<<(N + 63) / 64, 256, 0, stream>>>(Hs, bat, pooled, N);
    ffn_kernel<<<G, 256, 0, stream>>>(pooled, goff, Wf, bf, Wo, bo, out);
}